// Round 9
// baseline (203.501 us; speedup 1.0000x reference)
//
#include <hip/hip_runtime.h>

#define HW 16384

typedef _Float16 f16;
typedef __attribute__((ext_vector_type(4))) float f32x4;
typedef __attribute__((ext_vector_type(8))) _Float16 f16x8;
typedef __attribute__((ext_vector_type(4))) int i32x4;

union h8i4 { f16x8 h; i32x4 i; };

static __device__ __forceinline__ int pk_f16(float lo, float hi) {
    int r;
    asm("v_cvt_pkrtz_f16_f32 %0, %1, %2" : "=v"(r) : "v"(lo), "v"(hi));
    return r;
}
static __device__ __forceinline__ f16 ush2h(unsigned short u) {
    union { unsigned short s; f16 h; } c; c.s = u; return c.h;
}

// ---------------- prep: transpose x -> NHWC f16, weights -> fragment order ----------------
__global__ __launch_bounds__(256) void prep_kernel(
    const float* __restrict__ x, const float* __restrict__ wd,
    const float* __restrict__ woff,
    f16* __restrict__ xT, f16* __restrict__ Wc2, f16* __restrict__ Wo2)
{
    int bid = blockIdx.x;
    int tid = threadIdx.x;
    if (bid < 2048) {
        __shared__ float tl[64][65];
        int ct = bid & 3, pt = (bid >> 2) & 255, b = bid >> 10;
        const float* xb = x + ((size_t)(b * 256 + ct * 64)) * HW + pt * 64;
        #pragma unroll
        for (int j = 0; j < 4; ++j) {
            int slot = tid + j * 256;            // 1024 = 64 ch * 16 quads
            int c = slot >> 4, p4 = slot & 15;
            float4 v = *(const float4*)(xb + (size_t)c * HW + p4 * 4);
            tl[c][p4 * 4 + 0] = v.x;
            tl[c][p4 * 4 + 1] = v.y;
            tl[c][p4 * 4 + 2] = v.z;
            tl[c][p4 * 4 + 3] = v.w;
        }
        __syncthreads();
        f16* ob = xT + ((size_t)(b * HW + pt * 64)) * 256 + ct * 64;
        #pragma unroll
        for (int j2 = 0; j2 < 2; ++j2) {
            int slot = tid + j2 * 256;           // 512 = 64 pix * 8 slices
            int p = slot >> 3, sl = slot & 7;
            i32x4 st;
            #pragma unroll
            for (int kq = 0; kq < 4; ++kq)
                ((int*)&st)[kq] = pk_f16(tl[sl*8 + kq*2][p], tl[sl*8 + kq*2 + 1][p]);
            *(i32x4*)(ob + (size_t)p * 256 + sl * 8) = st;
        }
    } else if (bid < 2336) {
        // slot = kc*2048 + q4*512 + mi*128 + ks*64 + lane ; 8 f16 each
        int slot = (bid - 2048) * 256 + tid;     // 0..73727
        int l  = slot & 63;
        int ks = (slot >> 6) & 1;
        int mi = (slot >> 7) & 3;
        int q4 = (slot >> 9) & 3;
        int kc = slot >> 11;                     // 0..35 = g*9+tap
        int g = kc / 9, tap = kc - g * 9;
        int o = q4 * 64 + mi * 16 + (l & 15);
        int cgb = (ks * 4 + (l >> 4)) * 8;
        f16* dst = Wc2 + (size_t)slot * 8;
        const float* src = wd + (size_t)o * 2304 + tap;
        #pragma unroll
        for (int e = 0; e < 8; ++e)
            dst[e] = (f16)(src[(size_t)(g * 64 + cgb + e) * 9]);
    } else {
        int slot = (bid - 2336) * 256 + tid;     // 0..2559 b128 slots
        int kk = slot / 320;
        int rem = slot - kk * 320;
        int o = rem >> 2, jq = rem & 3;
        f16* dst = Wo2 + (size_t)slot * 8;
        #pragma unroll
        for (int e = 0; e < 8; ++e)
            dst[e] = (o < 72) ? (f16)(woff[(size_t)o * 256 + kk * 32 + jq * 8 + e]) : (f16)0.f;
    }
}

struct GS { f16x8 v00, v01, v10, v11; int wz, ww; };

// ---------------- main: fused offsets (MFMA) + deformable conv (MFMA, 2-chunk staged) + ReLU --------
__global__ __launch_bounds__(512, 4) void deform_kernel(
    const f16* __restrict__ xT, const f16* __restrict__ Wc2,
    const f16* __restrict__ Wo2, const float* __restrict__ b_off,
    float* __restrict__ out)
{
    __shared__ __align__(16) i32x4 pkt[2304];       // {idx00, idx11, pk(w00,w01), pk(w10,w11)}
    __shared__ __align__(16) short Sbuf[2][8192];   // 2 stages x 2 chunks x [64 pix][64 ch] f16

    const int t    = threadIdx.x;
    const int lane = t & 63;
    const int q    = t >> 6;                 // wave 0..7
    const int lr   = lane & 15, lq = lane >> 4;
    int bid = blockIdx.x;
    bid = (bid & 7) * 64 + (bid >> 3);       // XCD-aware swizzle (512 % 8 == 0)
    const int gp0  = bid << 6;
    const int b    = gp0 >> 14;
    const int hw0  = gp0 & 16383;
    const int h    = hw0 >> 7;
    const int w0   = hw0 & 127;

    // ---- phase 1: 72 offset channels via MFMA; pack geometry into pkt[] ----
    {
        const int p16 = (q & 3) * 16;
        f16x8 xv[8];
        const f16* xrow = xT + ((size_t)(b * HW + hw0 + p16 + lr)) * 256 + lq * 8;
        #pragma unroll
        for (int kk = 0; kk < 8; ++kk)
            xv[kk] = *(const f16x8*)(xrow + kk * 32);
        const int mi0 = (q < 4) ? 0 : 3;
        const int nmi = (q < 4) ? 3 : 2;
        for (int im = 0; im < nmi; ++im) {
            int mi = mi0 + im;
            f32x4 oa = (f32x4)0.f;
            #pragma unroll
            for (int kk = 0; kk < 8; ++kk) {
                f16x8 af = *(const f16x8*)(Wo2 + (size_t)((kk * 80 + mi * 16 + lr) * 32 + lq * 8));
                oa = __builtin_amdgcn_mfma_f32_16x16x32_f16(af, xv[kk], oa, 0, 0, 0);
            }
            #pragma unroll
            for (int ri = 0; ri < 2; ++ri) {
                int gt = mi * 8 + lq * 2 + ri;
                if (gt < 36) {
                    int p = p16 + lr;
                    float dy = oa[ri * 2]     + b_off[2 * gt];
                    float dx = oa[ri * 2 + 1] + b_off[2 * gt + 1];
                    int tap = gt % 9;
                    float ys = (float)(h - 1 + tap / 3) + dy;
                    float xs = (float)(w0 + p - 1 + tap % 3) + dx;
                    float fy = floorf(ys), fx = floorf(xs);
                    int y0 = (int)fy, x0 = (int)fx;
                    float ly = ys - fy, lx = xs - fx;
                    float omy = 1.f - ly, omx = 1.f - lx;
                    float vy0 = ((unsigned)y0       < 128u) ? 1.f : 0.f;
                    float vy1 = ((unsigned)(y0 + 1) < 128u) ? 1.f : 0.f;
                    float vx0 = ((unsigned)x0       < 128u) ? 1.f : 0.f;
                    float vx1 = ((unsigned)(x0 + 1) < 128u) ? 1.f : 0.f;
                    int y0c = min(max(y0, 0), 127), y1c = min(max(y0 + 1, 0), 127);
                    int x0c = min(max(x0, 0), 127), x1c = min(max(x0 + 1, 0), 127);
                    i32x4 e;
                    e.x = y0c * 128 + x0c;
                    e.y = y1c * 128 + x1c;
                    e.z = pk_f16(omy * omx * vy0 * vx0, omy * lx * vy0 * vx1);
                    e.w = pk_f16(ly  * omx * vy1 * vx0, ly  * lx * vy1 * vx1);
                    pkt[gt * 64 + p] = e;
                }
            }
        }
    }
    __syncthreads();

    f32x4 acc[2][4];
    #pragma unroll
    for (int mi = 0; mi < 2; ++mi)
        #pragma unroll
        for (int nj = 0; nj < 4; ++nj)
            acc[mi][nj] = (f32x4)0.f;

    const f16* xbase = xT + ((size_t)b * HW) * 256;
    const int ppix = q * 8 + (lane >> 3);    // S-build: this lane's pixel
    const int sl   = lane & 7;               // S-build: 8-channel slice
    const int q4   = q >> 1;
    const int mo   = (q & 1) * 2;

    auto issue_chunk = [&](int kc, GS& gs) {
        int grp = kc / 9;
        i32x4 cd = pkt[kc * 64 + ppix];
        int idx00 = cd.x, idx11 = cd.y;
        int idx01 = (idx00 & ~127) | (idx11 & 127);
        int idx10 = (idx11 & ~127) | (idx00 & 127);
        const f16* cb = xbase + (size_t)(grp * 64 + sl * 8);
        gs.v00 = *(const f16x8*)(cb + (size_t)idx00 * 256);
        gs.v01 = *(const f16x8*)(cb + (size_t)idx01 * 256);
        gs.v10 = *(const f16x8*)(cb + (size_t)idx10 * 256);
        gs.v11 = *(const f16x8*)(cb + (size_t)idx11 * 256);
        gs.wz = cd.z; gs.ww = cd.w;
    };
    auto interp_chunk = [&](const GS& gs, short* Sh) {
        f16x8 w00v = (f16x8)ush2h((unsigned short)(gs.wz & 0xffff));
        f16x8 w01v = (f16x8)ush2h((unsigned short)((unsigned)gs.wz >> 16));
        f16x8 w10v = (f16x8)ush2h((unsigned short)(gs.ww & 0xffff));
        f16x8 w11v = (f16x8)ush2h((unsigned short)((unsigned)gs.ww >> 16));
        f16x8 sv = gs.v00 * w00v;
        sv += gs.v01 * w01v;
        sv += gs.v10 * w10v;
        sv += gs.v11 * w11v;
        h8i4 u; u.h = sv;
        ((i32x4*)Sh)[ppix * 8 + (sl ^ (ppix & 7))] = u.i;
    };
    auto mfma_chunk = [&](int kc, const short* Sh) {
        f16x8 a_[2][2];
        const f16* wb = Wc2 + ((size_t)kc * 2048 + q4 * 512 + mo * 128 + lane) * 8;
        #pragma unroll
        for (int mi = 0; mi < 2; ++mi)
            #pragma unroll
            for (int ks = 0; ks < 2; ++ks)
                a_[mi][ks] = *(const f16x8*)(wb + (mi * 128 + ks * 64) * 8);
        #pragma unroll
        for (int ks = 0; ks < 2; ++ks) {
            f16x8 bb[4];
            #pragma unroll
            for (int nj = 0; nj < 4; ++nj) {
                int pp = nj * 16 + lr;
                h8i4 u;
                u.i = ((const i32x4*)Sh)[pp * 8 + ((ks * 4 + lq) ^ (pp & 7))];
                bb[nj] = u.h;
            }
            #pragma unroll
            for (int mi = 0; mi < 2; ++mi)
                #pragma unroll
                for (int nj = 0; nj < 4; ++nj)
                    acc[mi][nj] = __builtin_amdgcn_mfma_f32_16x16x32_f16(
                        a_[mi][ks], bb[nj], acc[mi][nj], 0, 0, 0);
        }
    };

    GS A0, A1, B0, B1;
    issue_chunk(0, A0); issue_chunk(1, A1);

    for (int s = 0; s < 18; s += 2) {
        const int c0 = s * 2;
        // ---- even stage s: chunks c0,c0+1 (regs A) -> Sbuf[0]; prefetch stage s+1 into B ----
        issue_chunk(c0 + 2, B0); issue_chunk(c0 + 3, B1);
        interp_chunk(A0, Sbuf[0]); interp_chunk(A1, Sbuf[0] + 4096);
        __syncthreads();
        __builtin_amdgcn_s_setprio(1);
        mfma_chunk(c0,     Sbuf[0]);
        mfma_chunk(c0 + 1, Sbuf[0] + 4096);
        __builtin_amdgcn_s_setprio(0);
        // ---- odd stage s+1: chunks c0+2,c0+3 (regs B) -> Sbuf[1]; prefetch stage s+2 into A ----
        if (s < 16) { issue_chunk(c0 + 4, A0); issue_chunk(c0 + 5, A1); }
        interp_chunk(B0, Sbuf[1]); interp_chunk(B1, Sbuf[1] + 4096);
        __syncthreads();
        __builtin_amdgcn_s_setprio(1);
        mfma_chunk(c0 + 2, Sbuf[1]);
        mfma_chunk(c0 + 3, Sbuf[1] + 4096);
        __builtin_amdgcn_s_setprio(0);
    }

    // ---- epilogue: ReLU + store ----
    #pragma unroll
    for (int mi = 0; mi < 2; ++mi)
        #pragma unroll
        for (int nj = 0; nj < 4; ++nj)
            #pragma unroll
            for (int r = 0; r < 4; ++r) {
                int o  = q * 32 + mi * 16 + lq * 4 + r;
                int pp = nj * 16 + lr;
                out[((size_t)(b * 256 + o) << 14) + hw0 + pp] = fmaxf(acc[mi][nj][r], 0.f);
            }
}

extern "C" void kernel_launch(void* const* d_in, const int* in_sizes, int n_in,
                              void* d_out, int out_size, void* d_ws, size_t ws_size,
                              hipStream_t stream) {
    const float* x     = (const float*)d_in[0];   // [2,256,128,128]
    const float* w_off = (const float*)d_in[1];   // [72,256,1,1]
    const float* b_off = (const float*)d_in[2];   // [72]
    const float* w_def = (const float*)d_in[3];   // [256,256,3,3]
    float* out = (float*)d_out;

    f16* xT  = (f16*)d_ws;                     // 16.78 MB
    f16* Wc2 = (f16*)((char*)d_ws + 16777216); // 1.18 MB
    f16* Wo2 = (f16*)((char*)d_ws + 17956864); // 40 KB

    prep_kernel<<<2346, 256, 0, stream>>>(x, w_def, w_off, xT, Wc2, Wo2);
    deform_kernel<<<512, 512, 0, stream>>>(xT, Wc2, Wo2, b_off, out);
}

// Round 11
// 153.394 us; speedup vs baseline: 1.3267x; 1.3267x over previous
//
#include <hip/hip_runtime.h>

#define HW 16384

typedef _Float16 f16;
typedef __attribute__((ext_vector_type(4))) float f32x4;
typedef __attribute__((ext_vector_type(8))) _Float16 f16x8;
typedef __attribute__((ext_vector_type(4))) int i32x4;

union h8i4 { f16x8 h; i32x4 i; };

static __device__ __forceinline__ int pk_f16(float lo, float hi) {
    int r;
    asm("v_cvt_pkrtz_f16_f32 %0, %1, %2" : "=v"(r) : "v"(lo), "v"(hi));
    return r;
}
static __device__ __forceinline__ f16 ush2h(unsigned short u) {
    union { unsigned short s; f16 h; } c; c.s = u; return c.h;
}

// ---------------- prep: transpose x -> NHWC f16, weights -> fragment order ----------------
__global__ __launch_bounds__(256) void prep_kernel(
    const float* __restrict__ x, const float* __restrict__ wd,
    const float* __restrict__ woff,
    f16* __restrict__ xT, f16* __restrict__ Wc2, f16* __restrict__ Wo2)
{
    int bid = blockIdx.x;
    int tid = threadIdx.x;
    if (bid < 2048) {
        __shared__ float tl[64][65];
        int ct = bid & 3, pt = (bid >> 2) & 255, b = bid >> 10;
        const float* xb = x + ((size_t)(b * 256 + ct * 64)) * HW + pt * 64;
        #pragma unroll
        for (int j = 0; j < 4; ++j) {
            int slot = tid + j * 256;            // 1024 = 64 ch * 16 quads
            int c = slot >> 4, p4 = slot & 15;
            float4 v = *(const float4*)(xb + (size_t)c * HW + p4 * 4);
            tl[c][p4 * 4 + 0] = v.x;
            tl[c][p4 * 4 + 1] = v.y;
            tl[c][p4 * 4 + 2] = v.z;
            tl[c][p4 * 4 + 3] = v.w;
        }
        __syncthreads();
        f16* ob = xT + ((size_t)(b * HW + pt * 64)) * 256 + ct * 64;
        #pragma unroll
        for (int j2 = 0; j2 < 2; ++j2) {
            int slot = tid + j2 * 256;           // 512 = 64 pix * 8 slices
            int p = slot >> 3, sl = slot & 7;
            i32x4 st;
            #pragma unroll
            for (int kq = 0; kq < 4; ++kq)
                ((int*)&st)[kq] = pk_f16(tl[sl*8 + kq*2][p], tl[sl*8 + kq*2 + 1][p]);
            *(i32x4*)(ob + (size_t)p * 256 + sl * 8) = st;
        }
    } else if (bid < 2336) {
        // slot = kc*2048 + q4*512 + mi*128 + ks*64 + lane ; 8 f16 each
        int slot = (bid - 2048) * 256 + tid;     // 0..73727
        int l  = slot & 63;
        int ks = (slot >> 6) & 1;
        int mi = (slot >> 7) & 3;
        int q4 = (slot >> 9) & 3;
        int kc = slot >> 11;                     // 0..35 = g*9+tap
        int g = kc / 9, tap = kc - g * 9;
        int o = q4 * 64 + mi * 16 + (l & 15);
        int cgb = (ks * 4 + (l >> 4)) * 8;
        f16* dst = Wc2 + (size_t)slot * 8;
        const float* src = wd + (size_t)o * 2304 + tap;
        #pragma unroll
        for (int e = 0; e < 8; ++e)
            dst[e] = (f16)(src[(size_t)(g * 64 + cgb + e) * 9]);
    } else {
        int slot = (bid - 2336) * 256 + tid;     // 0..2559 b128 slots
        int kk = slot / 320;
        int rem = slot - kk * 320;
        int o = rem >> 2, jq = rem & 3;
        f16* dst = Wo2 + (size_t)slot * 8;
        #pragma unroll
        for (int e = 0; e < 8; ++e)
            dst[e] = (o < 72) ? (f16)(woff[(size_t)o * 256 + kk * 32 + jq * 8 + e]) : (f16)0.f;
    }
}

struct GS { f16x8 v00, v01, v10, v11; };   // data only: 16 VGPRs

// ---------------- main: fused offsets (MFMA) + deformable conv (MFMA, depth-2 prefetch) + ReLU ------
__global__ __launch_bounds__(512, 4) void deform_kernel(
    const f16* __restrict__ xT, const f16* __restrict__ Wc2,
    const f16* __restrict__ Wo2, const float* __restrict__ b_off,
    float* __restrict__ out)
{
    __shared__ __align__(16) i32x4 pkt[2304];       // {idx00, idx11, pk(w00,w01), pk(w10,w11)}
    __shared__ __align__(16) short Sbuf[2][4096];   // double-buffered S tile [64 pix][64 ch] f16

    const int t    = threadIdx.x;
    const int lane = t & 63;
    const int q    = t >> 6;                 // wave 0..7
    const int lr   = lane & 15, lq = lane >> 4;
    int bid = blockIdx.x;
    bid = (bid & 7) * 64 + (bid >> 3);       // XCD-aware swizzle (512 % 8 == 0)
    const int gp0  = bid << 6;
    const int b    = gp0 >> 14;
    const int hw0  = gp0 & 16383;
    const int h    = hw0 >> 7;
    const int w0   = hw0 & 127;

    // ---- phase 1: 72 offset channels via MFMA; pack geometry into pkt[] ----
    {
        const int p16 = (q & 3) * 16;
        f16x8 xv[8];
        const f16* xrow = xT + ((size_t)(b * HW + hw0 + p16 + lr)) * 256 + lq * 8;
        #pragma unroll
        for (int kk = 0; kk < 8; ++kk)
            xv[kk] = *(const f16x8*)(xrow + kk * 32);
        const int mi0 = (q < 4) ? 0 : 3;
        const int nmi = (q < 4) ? 3 : 2;
        for (int im = 0; im < nmi; ++im) {
            int mi = mi0 + im;
            f32x4 oa = (f32x4)0.f;
            #pragma unroll
            for (int kk = 0; kk < 8; ++kk) {
                f16x8 af = *(const f16x8*)(Wo2 + (size_t)((kk * 80 + mi * 16 + lr) * 32 + lq * 8));
                oa = __builtin_amdgcn_mfma_f32_16x16x32_f16(af, xv[kk], oa, 0, 0, 0);
            }
            #pragma unroll
            for (int ri = 0; ri < 2; ++ri) {
                int gt = mi * 8 + lq * 2 + ri;
                if (gt < 36) {
                    int p = p16 + lr;
                    float dy = oa[ri * 2]     + b_off[2 * gt];
                    float dx = oa[ri * 2 + 1] + b_off[2 * gt + 1];
                    int tap = gt % 9;
                    float ys = (float)(h - 1 + tap / 3) + dy;
                    float xs = (float)(w0 + p - 1 + tap % 3) + dx;
                    float fy = floorf(ys), fx = floorf(xs);
                    int y0 = (int)fy, x0 = (int)fx;
                    float ly = ys - fy, lx = xs - fx;
                    float omy = 1.f - ly, omx = 1.f - lx;
                    float vy0 = ((unsigned)y0       < 128u) ? 1.f : 0.f;
                    float vy1 = ((unsigned)(y0 + 1) < 128u) ? 1.f : 0.f;
                    float vx0 = ((unsigned)x0       < 128u) ? 1.f : 0.f;
                    float vx1 = ((unsigned)(x0 + 1) < 128u) ? 1.f : 0.f;
                    int y0c = min(max(y0, 0), 127), y1c = min(max(y0 + 1, 0), 127);
                    int x0c = min(max(x0, 0), 127), x1c = min(max(x0 + 1, 0), 127);
                    i32x4 e;
                    e.x = y0c * 128 + x0c;
                    e.y = y1c * 128 + x1c;
                    e.z = pk_f16(omy * omx * vy0 * vx0, omy * lx * vy0 * vx1);
                    e.w = pk_f16(ly  * omx * vy1 * vx0, ly  * lx * vy1 * vx1);
                    pkt[gt * 64 + p] = e;
                }
            }
        }
    }
    __syncthreads();

    f32x4 acc[2][4];
    #pragma unroll
    for (int mi = 0; mi < 2; ++mi)
        #pragma unroll
        for (int nj = 0; nj < 4; ++nj)
            acc[mi][nj] = (f32x4)0.f;

    const f16* xbase = xT + ((size_t)b * HW) * 256;
    const int ppix = q * 8 + (lane >> 3);    // S-build: this lane's pixel
    const int sl   = lane & 7;               // S-build: 8-channel slice
    const int q4   = q >> 1;
    const int mo   = (q & 1) * 2;

    auto issue_chunk = [&](int kc, GS& gs) {
        int grp = kc / 9;
        int2 c2 = *(const int2*)&pkt[kc * 64 + ppix];
        int idx00 = c2.x, idx11 = c2.y;
        int idx01 = (idx00 & ~127) | (idx11 & 127);
        int idx10 = (idx11 & ~127) | (idx00 & 127);
        const f16* cb = xbase + (size_t)(grp * 64 + sl * 8);
        gs.v00 = *(const f16x8*)(cb + (size_t)idx00 * 256);
        gs.v01 = *(const f16x8*)(cb + (size_t)idx01 * 256);
        gs.v10 = *(const f16x8*)(cb + (size_t)idx10 * 256);
        gs.v11 = *(const f16x8*)(cb + (size_t)idx11 * 256);
    };
    auto interp_chunk = [&](int kc, const GS& gs, short* Sh) {
        int2 wzw = *(const int2*)(((const int*)&pkt[kc * 64 + ppix]) + 2);
        f16x8 w00v = (f16x8)ush2h((unsigned short)(wzw.x & 0xffff));
        f16x8 w01v = (f16x8)ush2h((unsigned short)((unsigned)wzw.x >> 16));
        f16x8 w10v = (f16x8)ush2h((unsigned short)(wzw.y & 0xffff));
        f16x8 w11v = (f16x8)ush2h((unsigned short)((unsigned)wzw.y >> 16));
        f16x8 sv = gs.v00 * w00v;
        sv += gs.v01 * w01v;
        sv += gs.v10 * w10v;
        sv += gs.v11 * w11v;
        h8i4 u; u.h = sv;
        ((i32x4*)Sh)[ppix * 8 + (sl ^ (ppix & 7))] = u.i;
    };
    auto mfma_chunk = [&](int kc, const short* Sh) {
        f16x8 a_[2][2];
        const f16* wb = Wc2 + ((size_t)kc * 2048 + q4 * 512 + mo * 128 + lane) * 8;
        #pragma unroll
        for (int mi = 0; mi < 2; ++mi)
            #pragma unroll
            for (int ks = 0; ks < 2; ++ks)
                a_[mi][ks] = *(const f16x8*)(wb + (mi * 128 + ks * 64) * 8);
        #pragma unroll
        for (int ks = 0; ks < 2; ++ks) {
            f16x8 bb[4];
            #pragma unroll
            for (int nj = 0; nj < 4; ++nj) {
                int pp = nj * 16 + lr;
                h8i4 u;
                u.i = ((const i32x4*)Sh)[pp * 8 + ((ks * 4 + lq) ^ (pp & 7))];
                bb[nj] = u.h;
            }
            #pragma unroll
            for (int mi = 0; mi < 2; ++mi)
                #pragma unroll
                for (int nj = 0; nj < 4; ++nj)
                    acc[mi][nj] = __builtin_amdgcn_mfma_f32_16x16x32_f16(
                        a_[mi][ks], bb[nj], acc[mi][nj], 0, 0, 0);
        }
    };

    // depth-2 gather prefetch, 2 slots: at iter kc, slot[kc&1] gets kc+2,
    // slot[(kc+1)&1] (loaded 2 iters ago) is interped for kc+1.
    GS ga, gb;
    issue_chunk(0, ga); issue_chunk(1, gb);
    interp_chunk(0, ga, Sbuf[0]);
    __syncthreads();

    for (int s = 0; s < 36; s += 2) {
        // ---- even iter s: mfma Sbuf[0]; interp s+1 (gb) -> Sbuf[1]; issue s+2 -> ga ----
        if (s + 2 < 36) issue_chunk(s + 2, ga);
        __builtin_amdgcn_s_setprio(1);
        mfma_chunk(s, Sbuf[0]);
        __builtin_amdgcn_s_setprio(0);
        interp_chunk(s + 1, gb, Sbuf[1]);
        __syncthreads();
        // ---- odd iter s+1: mfma Sbuf[1]; interp s+2 (ga) -> Sbuf[0]; issue s+3 -> gb ----
        if (s + 3 < 36) issue_chunk(s + 3, gb);
        __builtin_amdgcn_s_setprio(1);
        mfma_chunk(s + 1, Sbuf[1]);
        __builtin_amdgcn_s_setprio(0);
        if (s + 2 < 36) interp_chunk(s + 2, ga, Sbuf[0]);
        __syncthreads();
    }

    // ---- epilogue: ReLU + store ----
    #pragma unroll
    for (int mi = 0; mi < 2; ++mi)
        #pragma unroll
        for (int nj = 0; nj < 4; ++nj)
            #pragma unroll
            for (int r = 0; r < 4; ++r) {
                int o  = q * 32 + mi * 16 + lq * 4 + r;
                int pp = nj * 16 + lr;
                out[((size_t)(b * 256 + o) << 14) + hw0 + pp] = fmaxf(acc[mi][nj][r], 0.f);
            }
}

extern "C" void kernel_launch(void* const* d_in, const int* in_sizes, int n_in,
                              void* d_out, int out_size, void* d_ws, size_t ws_size,
                              hipStream_t stream) {
    const float* x     = (const float*)d_in[0];   // [2,256,128,128]
    const float* w_off = (const float*)d_in[1];   // [72,256,1,1]
    const float* b_off = (const float*)d_in[2];   // [72]
    const float* w_def = (const float*)d_in[3];   // [256,256,3,3]
    float* out = (float*)d_out;

    f16* xT  = (f16*)d_ws;                     // 16.78 MB
    f16* Wc2 = (f16*)((char*)d_ws + 16777216); // 1.18 MB
    f16* Wo2 = (f16*)((char*)d_ws + 17956864); // 40 KB

    prep_kernel<<<2346, 256, 0, stream>>>(x, w_def, w_off, xT, Wc2, Wo2);
    deform_kernel<<<512, 512, 0, stream>>>(xT, Wc2, Wo2, b_off, out);
}